// Round 2
// baseline (1050.368 us; speedup 1.0000x reference)
//
#include <hip/hip_runtime.h>
#include <hip/hip_bf16.h>
#include <stdint.h>

// Problem constants (from reference)
#define E_EDGES 1048576
#define NN 50000
#define NODE_H 128
#define EDGE_H 64
#define GNN_H 128
#define K1 320  // 2*NODE_H + EDGE_H
#define K2 256  // NODE_H + GNN_H
#define NB 16   // nodes per block in fused kernel

typedef __bf16 bf16_t;
typedef __bf16 bf16x8 __attribute__((ext_vector_type(8)));
typedef float floatx4 __attribute__((ext_vector_type(4)));

// Workspace layout (bytes)
#define OFF_FLAG 0
#define OFF_CNT 256                        // int cnt[NN] (sorted path) -- 200000B
#define OFF_RP (OFF_CNT + 200192)          // int rowptr[NN+1]
#define OFF_WOFF (OFF_RP + 200448)         // int woff[NN]  (also float cnt, old path)
#define OFF_PERM (OFF_WOFF + 200192)       // uint perm[E]
#define OFF_W1T (OFF_PERM + E_EDGES * 4)   // bf16 W1^T [128][320]
#define OFF_W2T (OFF_W1T + K1 * GNN_H * 2) // bf16 W2^T [128][256]
#define OFF_S (OFF_W2T + K2 * GNN_H * 2)
#define WS_SORT ((size_t)OFF_S)                          // ~4.94 MB
#define WS_OLD (WS_SORT + (size_t)NN * GNN_H * 4)        // ~30.5 MB

__device__ __forceinline__ long load_idx(const void* ei, int is64, long off) {
    return is64 ? (long)((const long long*)ei)[off] : (long)((const int*)ei)[off];
}

// Prep: transpose W1,W2 to bf16 [N][K]; detect edge_index dtype.
__global__ void prep_kernel(const float* __restrict__ W1, const float* __restrict__ W2,
                            const int* __restrict__ ei32, char* __restrict__ ws) {
    bf16_t* w1t = (bf16_t*)(ws + OFF_W1T);
    bf16_t* w2t = (bf16_t*)(ws + OFF_W2T);
    int tid = blockIdx.x * blockDim.x + threadIdx.x;
    int nt = gridDim.x * blockDim.x;
    for (int i = tid; i < K1 * GNN_H; i += nt) {
        int n = i / K1, k = i - n * K1;
        w1t[i] = (bf16_t)W1[k * GNN_H + n];
    }
    for (int i = tid; i < K2 * GNN_H; i += nt) {
        int n = i / K2, k = i - n * K2;
        w2t[i] = (bf16_t)W2[k * GNN_H + n];
    }
    if (blockIdx.x == 0) {
        __shared__ int any_nonzero;
        if (threadIdx.x == 0) any_nonzero = 0;
        __syncthreads();
        if (ei32[2 * threadIdx.x + 1] != 0) atomicOr(&any_nonzero, 1);
        __syncthreads();
        if (threadIdx.x == 0) *(int*)(ws + OFF_FLAG) = (any_nonzero == 0) ? 1 : 0;
    }
}

// ---------------- sorted (fast) path ----------------

__global__ void hist_kernel(const void* __restrict__ ei, const char* __restrict__ ws,
                            int* __restrict__ cnt) {
    int is64 = *(const int*)(ws + OFF_FLAG);
    int e = blockIdx.x * blockDim.x + threadIdx.x;
    if (e < E_EDGES) {
        long c = load_idx(ei, is64, (long)E_EDGES + e);
        atomicAdd(cnt + c, 1);
    }
}

__global__ __launch_bounds__(1024) void scan_kernel(const int* __restrict__ cnt,
                                                    int* __restrict__ rowptr,
                                                    int* __restrict__ woff) {
    __shared__ int part[1024];
    int t = threadIdx.x;
    const int CH = (NN + 1023) / 1024;  // 49
    int base = t * CH;
    int n = NN - base;
    if (n < 0) n = 0;
    if (n > CH) n = CH;
    int s = 0;
    for (int i = 0; i < n; ++i) s += cnt[base + i];
    part[t] = s;
    __syncthreads();
    for (int off = 1; off < 1024; off <<= 1) {
        int v = (t >= off) ? part[t - off] : 0;
        __syncthreads();
        part[t] += v;
        __syncthreads();
    }
    int run = part[t] - s;  // exclusive prefix
    for (int i = 0; i < n; ++i) {
        rowptr[base + i] = run;
        woff[base + i] = run;
        run += cnt[base + i];
    }
    if (t == 1023) rowptr[NN] = part[1023];
}

__global__ void scatter_kernel(const void* __restrict__ ei, const char* __restrict__ ws,
                               int* __restrict__ woff, unsigned* __restrict__ perm) {
    int is64 = *(const int*)(ws + OFF_FLAG);
    int e = blockIdx.x * blockDim.x + threadIdx.x;
    if (e < E_EDGES) {
        long c = load_idx(ei, is64, (long)E_EDGES + e);
        int pos = atomicAdd(woff + c, 1);
        perm[pos] = (unsigned)e;
    }
}

// Fused edge-MLP + scatter-mean + node-MLP. Block = 4 waves, owns NB=16 nodes.
// Wave w computes output cols [w*32, w*32+32). Edge messages accumulate into
// LDS agg via ds_add_f32 (no global atomics); node MLP fused at the tail.
__global__ __launch_bounds__(256) void fused_kernel(
    const float* __restrict__ x, const void* __restrict__ ei,
    const float* __restrict__ ea, const float* __restrict__ b1,
    const float* __restrict__ b2, const char* __restrict__ ws,
    float* __restrict__ out) {
    const bf16_t* w1t = (const bf16_t*)(ws + OFF_W1T);
    const bf16_t* w2t = (const bf16_t*)(ws + OFF_W2T);
    const int* rowptr = (const int*)(ws + OFF_RP);
    const int* cnt = (const int*)(ws + OFF_CNT);
    const unsigned* perm = (const unsigned*)(ws + OFF_PERM);
    int is64 = *(const int*)(ws + OFF_FLAG);

    __shared__ float agg[NB][132];  // stride 132 to spread banks

    int lane = threadIdx.x & 63;
    int w = threadIdx.x >> 6;
    int li = lane & 15;
    int h = lane >> 4;
    int n0 = w * 32;
    int v0 = blockIdx.x * NB;

    for (int i = threadIdx.x; i < NB * 132; i += 256) ((float*)agg)[i] = 0.f;

    // W1^T fragments in registers (80 VGPRs)
    bf16x8 bfr[2][10];
#pragma unroll
    for (int t = 0; t < 2; ++t)
#pragma unroll
        for (int ks = 0; ks < 10; ++ks)
            bfr[t][ks] = *(const bf16x8*)(w1t + (long)(n0 + t * 16 + li) * K1 + ks * 32 + h * 8);
    float bias0 = b1[n0 + li];
    float bias1 = b1[n0 + 16 + li];

    int e_beg = rowptr[v0];
    int e_end = rowptr[v0 + NB];
    __syncthreads();

    // Prefetched index state for software pipelining of the gather chain.
    unsigned ep = 0;
    long rowi = 0;
    int coli = v0;
    if (e_beg < e_end) {
        int e = e_beg + li;
        int ec = e < e_end ? e : e_end - 1;
        ep = perm[ec];
        rowi = load_idx(ei, is64, ep);
        coli = (int)load_idx(ei, is64, (long)E_EDGES + ep);
    }

    for (int e0 = e_beg; e0 < e_end; e0 += 16) {
        unsigned ep_c = ep;
        long rowi_c = rowi;
        int coli_c = coli;
        if (e0 + 16 < e_end) {  // prefetch next tile's indices
            int e = e0 + 16 + li;
            int ec = e < e_end ? e : e_end - 1;
            ep = perm[ec];
            rowi = load_idx(ei, is64, ep);
            coli = (int)load_idx(ei, is64, (long)E_EDGES + ep);
        }
        int nl = coli_c - v0;  // node-local index in [0, NB)
        const float* pr = x + rowi_c * NODE_H + h * 8;
        const float* pc = x + (long)coli_c * NODE_H + h * 8;
        const float* pe = ea + (long)ep_c * EDGE_H + h * 8;
        floatx4 acc0 = {0.f, 0.f, 0.f, 0.f};
        floatx4 acc1 = {0.f, 0.f, 0.f, 0.f};
#pragma unroll
        for (int ks = 0; ks < 10; ++ks) {
            const float* src = (ks < 4) ? (pr + ks * 32) : (ks < 8) ? (pc + (ks - 4) * 32)
                                                                    : (pe + (ks - 8) * 32);
            floatx4 f0 = *(const floatx4*)(src);
            floatx4 f1 = *(const floatx4*)(src + 4);
            bf16x8 a;
#pragma unroll
            for (int j = 0; j < 4; ++j) {
                a[j] = (bf16_t)f0[j];
                a[j + 4] = (bf16_t)f1[j];
            }
            acc0 = __builtin_amdgcn_mfma_f32_16x16x32_bf16(a, bfr[0][ks], acc0, 0, 0, 0);
            acc1 = __builtin_amdgcn_mfma_f32_16x16x32_bf16(a, bfr[1][ks], acc1, 0, 0, 0);
        }
        // C row r of this lane = edge e0 + 4h + r; its node-local col via shuffle.
#pragma unroll
        for (int r = 0; r < 4; ++r) {
            int er = e0 + h * 4 + r;
            int nlr = __shfl(nl, h * 4 + r, 64);
            if (er < e_end) {
                float m0 = fmaxf(acc0[r] + bias0, 0.f);
                float m1 = fmaxf(acc1[r] + bias1, 0.f);
                atomicAdd(&agg[nlr][n0 + li], m0);
                atomicAdd(&agg[nlr][n0 + 16 + li], m1);
            }
        }
    }
    __syncthreads();

    // Node MLP: out = relu([x, agg/cnt] @ W2 + b2) for nodes v0..v0+15.
    bf16x8 bfr2[2][8];
#pragma unroll
    for (int t = 0; t < 2; ++t)
#pragma unroll
        for (int ks = 0; ks < 8; ++ks)
            bfr2[t][ks] = *(const bf16x8*)(w2t + (long)(n0 + t * 16 + li) * K2 + ks * 32 + h * 8);
    float nb0 = b2[n0 + li];
    float nb1 = b2[n0 + 16 + li];

    int node = v0 + li;
    float rc = 1.0f / fmaxf((float)cnt[node], 1.0f);
    const float* px = x + (long)node * NODE_H + h * 8;
    floatx4 acc0 = {0.f, 0.f, 0.f, 0.f};
    floatx4 acc1 = {0.f, 0.f, 0.f, 0.f};
#pragma unroll
    for (int ks = 0; ks < 8; ++ks) {
        floatx4 f0, f1;
        if (ks < 4) {
            f0 = *(const floatx4*)(px + ks * 32);
            f1 = *(const floatx4*)(px + ks * 32 + 4);
        } else {
            const float* sa = &agg[li][(ks - 4) * 32 + h * 8];
            f0 = *(const floatx4*)(sa);
            f1 = *(const floatx4*)(sa + 4);
            f0 *= rc;
            f1 *= rc;
        }
        bf16x8 a;
#pragma unroll
        for (int j = 0; j < 4; ++j) {
            a[j] = (bf16_t)f0[j];
            a[j + 4] = (bf16_t)f1[j];
        }
        acc0 = __builtin_amdgcn_mfma_f32_16x16x32_bf16(a, bfr2[0][ks], acc0, 0, 0, 0);
        acc1 = __builtin_amdgcn_mfma_f32_16x16x32_bf16(a, bfr2[1][ks], acc1, 0, 0, 0);
    }
#pragma unroll
    for (int r = 0; r < 4; ++r) {
        long ir = v0 + h * 4 + r;
        out[ir * GNN_H + n0 + li] = fmaxf(acc0[r] + nb0, 0.f);
        out[ir * GNN_H + n0 + 16 + li] = fmaxf(acc1[r] + nb1, 0.f);
    }
}

// ---------------- fallback (v1) path ----------------

__global__ void count_kernel(const void* __restrict__ ei, const char* __restrict__ ws,
                             float* __restrict__ cnt) {
    int is64 = *(const int*)(ws + OFF_FLAG);
    int e = blockIdx.x * blockDim.x + threadIdx.x;
    if (e < E_EDGES) {
        long c = load_idx(ei, is64, (long)E_EDGES + e);
        atomicAdd(cnt + c, 1.0f);
    }
}

__global__ __launch_bounds__(256) void edge_kernel(
    const float* __restrict__ x, const void* __restrict__ ei,
    const float* __restrict__ ea, const float* __restrict__ b1,
    const char* __restrict__ ws, float* __restrict__ s) {
    const bf16_t* w1t = (const bf16_t*)(ws + OFF_W1T);
    int is64 = *(const int*)(ws + OFF_FLAG);
    int lane = threadIdx.x & 63;
    int w = threadIdx.x >> 6;
    int li = lane & 15;
    int h = lane >> 4;
    int n0 = w * 32;

    bf16x8 bf[2][10];
#pragma unroll
    for (int t = 0; t < 2; ++t)
#pragma unroll
        for (int ks = 0; ks < 10; ++ks)
            bf[t][ks] = *(const bf16x8*)(w1t + (long)(n0 + t * 16 + li) * K1 + ks * 32 + h * 8);
    float bias0 = b1[n0 + li];
    float bias1 = b1[n0 + 16 + li];

    const int ntiles = E_EDGES / 16;
    for (int tile = blockIdx.x; tile < ntiles; tile += gridDim.x) {
        int m0 = tile * 16;
        int e = m0 + li;
        long rowi = load_idx(ei, is64, e);
        long coli = load_idx(ei, is64, (long)E_EDGES + e);
        const float* pr = x + rowi * NODE_H + h * 8;
        const float* pc = x + coli * NODE_H + h * 8;
        const float* pe = ea + (long)e * EDGE_H + h * 8;
        floatx4 acc0 = {0.f, 0.f, 0.f, 0.f};
        floatx4 acc1 = {0.f, 0.f, 0.f, 0.f};
#pragma unroll
        for (int ks = 0; ks < 10; ++ks) {
            const float* src = (ks < 4) ? (pr + ks * 32) : (ks < 8) ? (pc + (ks - 4) * 32)
                                                                    : (pe + (ks - 8) * 32);
            floatx4 f0 = *(const floatx4*)(src);
            floatx4 f1 = *(const floatx4*)(src + 4);
            bf16x8 a;
#pragma unroll
            for (int j = 0; j < 4; ++j) {
                a[j] = (bf16_t)f0[j];
                a[j + 4] = (bf16_t)f1[j];
            }
            acc0 = __builtin_amdgcn_mfma_f32_16x16x32_bf16(a, bf[0][ks], acc0, 0, 0, 0);
            acc1 = __builtin_amdgcn_mfma_f32_16x16x32_bf16(a, bf[1][ks], acc1, 0, 0, 0);
        }
        long cols[4];
#pragma unroll
        for (int r = 0; r < 4; ++r)
            cols[r] = load_idx(ei, is64, (long)E_EDGES + m0 + h * 4 + r);
#pragma unroll
        for (int r = 0; r < 4; ++r) {
            float v0 = fmaxf(acc0[r] + bias0, 0.f);
            float v1 = fmaxf(acc1[r] + bias1, 0.f);
            atomicAdd(s + cols[r] * GNN_H + n0 + li, v0);
            atomicAdd(s + cols[r] * GNN_H + n0 + 16 + li, v1);
        }
    }
}

__global__ __launch_bounds__(256) void node_kernel(
    const float* __restrict__ x, const float* __restrict__ b2,
    const char* __restrict__ ws, const float* __restrict__ cnt,
    const float* __restrict__ s, float* __restrict__ out) {
    const bf16_t* w2t = (const bf16_t*)(ws + OFF_W2T);
    int lane = threadIdx.x & 63;
    int w = threadIdx.x >> 6;
    int li = lane & 15;
    int h = lane >> 4;
    int n0 = w * 32;

    bf16x8 bf[2][8];
#pragma unroll
    for (int t = 0; t < 2; ++t)
#pragma unroll
        for (int ks = 0; ks < 8; ++ks)
            bf[t][ks] = *(const bf16x8*)(w2t + (long)(n0 + t * 16 + li) * K2 + ks * 32 + h * 8);
    float bias0 = b2[n0 + li];
    float bias1 = b2[n0 + 16 + li];

    int m0 = blockIdx.x * 16;
    int i = m0 + li;
    float rc = 1.0f / fmaxf(cnt[i], 1.0f);
    const float* px = x + (long)i * NODE_H + h * 8;
    const float* ps = s + (long)i * GNN_H + h * 8;
    floatx4 acc0 = {0.f, 0.f, 0.f, 0.f};
    floatx4 acc1 = {0.f, 0.f, 0.f, 0.f};
#pragma unroll
    for (int ks = 0; ks < 8; ++ks) {
        const float* src = (ks < 4) ? (px + ks * 32) : (ps + (ks - 4) * 32);
        floatx4 f0 = *(const floatx4*)(src);
        floatx4 f1 = *(const floatx4*)(src + 4);
        if (ks >= 4) {
            f0 *= rc;
            f1 *= rc;
        }
        bf16x8 a;
#pragma unroll
        for (int j = 0; j < 4; ++j) {
            a[j] = (bf16_t)f0[j];
            a[j + 4] = (bf16_t)f1[j];
        }
        acc0 = __builtin_amdgcn_mfma_f32_16x16x32_bf16(a, bf[0][ks], acc0, 0, 0, 0);
        acc1 = __builtin_amdgcn_mfma_f32_16x16x32_bf16(a, bf[1][ks], acc1, 0, 0, 0);
    }
    __syncthreads();  // allow s == out (in-place fallback)
#pragma unroll
    for (int r = 0; r < 4; ++r) {
        long ir = m0 + h * 4 + r;
        out[ir * GNN_H + n0 + li] = fmaxf(acc0[r] + bias0, 0.f);
        out[ir * GNN_H + n0 + 16 + li] = fmaxf(acc1[r] + bias1, 0.f);
    }
}

extern "C" void kernel_launch(void* const* d_in, const int* in_sizes, int n_in,
                              void* d_out, int out_size, void* d_ws, size_t ws_size,
                              hipStream_t stream) {
    const float* x = (const float*)d_in[0];
    const void* ei = d_in[1];
    const float* ea = (const float*)d_in[2];
    const float* W1 = (const float*)d_in[3];
    const float* b1 = (const float*)d_in[4];
    const float* W2 = (const float*)d_in[5];
    const float* b2 = (const float*)d_in[6];
    float* out = (float*)d_out;
    char* ws = (char*)d_ws;

    prep_kernel<<<32, 256, 0, stream>>>(W1, W2, (const int*)ei, ws);

    if (ws_size >= WS_SORT) {
        int* cnt = (int*)(ws + OFF_CNT);
        int* rowptr = (int*)(ws + OFF_RP);
        int* woff = (int*)(ws + OFF_WOFF);
        unsigned* perm = (unsigned*)(ws + OFF_PERM);
        hipMemsetAsync(cnt, 0, NN * 4, stream);
        hist_kernel<<<E_EDGES / 256, 256, 0, stream>>>(ei, ws, cnt);
        scan_kernel<<<1, 1024, 0, stream>>>(cnt, rowptr, woff);
        scatter_kernel<<<E_EDGES / 256, 256, 0, stream>>>(ei, ws, woff, perm);
        fused_kernel<<<NN / NB, 256, 0, stream>>>(x, ei, ea, b1, b2, ws, out);
    } else {
        float* cntf = (float*)(ws + OFF_WOFF);
        float* s = (ws_size >= WS_OLD) ? (float*)(ws + OFF_S) : out;
        hipMemsetAsync(cntf, 0, NN * 4, stream);
        hipMemsetAsync(s, 0, (size_t)NN * GNN_H * 4, stream);
        count_kernel<<<E_EDGES / 256, 256, 0, stream>>>(ei, ws, cntf);
        edge_kernel<<<4096, 256, 0, stream>>>(x, ei, ea, b1, ws, s);
        node_kernel<<<NN / 16, 256, 0, stream>>>(x, b2, ws, cntf, s, out);
    }
}

// Round 3
// 647.793 us; speedup vs baseline: 1.6215x; 1.6215x over previous
//
#include <hip/hip_runtime.h>
#include <hip/hip_bf16.h>
#include <stdint.h>

// Problem constants (from reference)
#define E_EDGES 1048576
#define NN 50000
#define NODE_H 128
#define EDGE_H 64
#define GNN_H 128
#define K1 320  // 2*NODE_H + EDGE_H
#define K2 256  // NODE_H + GNN_H
#define NB 16   // nodes per block in fused kernels

typedef __bf16 bf16_t;
typedef __bf16 bf16x8 __attribute__((ext_vector_type(8)));
typedef float floatx4 __attribute__((ext_vector_type(4)));

// Workspace layout (bytes)
#define OFF_FLAG 0
#define OFF_CNT 256          // int cnt[NN] (sorted) / float cnt (v1)   200192
#define OFF_W1T 200448       // bf16 W1^T [128][320]                     81920
#define OFF_W2T 282368       // bf16 W2^T [128][256]                     65536
#define OFF_W1ABT 347904     // bf16 [256][128]: n<128 -> W1a^T, else W1b^T
#define OFF_W1CT 413440      // bf16 W1c^T [128][64]                     16384
#define BASE_END 429824
#define OFF_RP 429824        // int rowptr[NN+1]                        200448
#define OFF_WOFF 630272      // int woff[NN]                            200192
#define OFF_PERM 830464      // uint perm[E]                           4194304
#define OFF_RC 5024768       // bf16 RC[NN][256]: [0:128]=x@W1a, [128:256]=x@W1b
#define WS_V2 ((size_t)OFF_RC)
#define WS_V3 ((size_t)OFF_RC + (size_t)NN * 256 * 2)  // ~30.6 MB

__device__ __forceinline__ long load_idx(const void* ei, int is64, long off) {
    return is64 ? (long)((const long long*)ei)[off] : (long)((const int*)ei)[off];
}

#define MFMA(a, b, c) __builtin_amdgcn_mfma_f32_16x16x32_bf16(a, b, c, 0, 0, 0)

// Prep: weight transforms + edge_index dtype probe.
__global__ void prep_kernel(const float* __restrict__ W1, const float* __restrict__ W2,
                            const int* __restrict__ ei32, char* __restrict__ ws) {
    bf16_t* w1t = (bf16_t*)(ws + OFF_W1T);
    bf16_t* w2t = (bf16_t*)(ws + OFF_W2T);
    bf16_t* w1abt = (bf16_t*)(ws + OFF_W1ABT);
    bf16_t* w1ct = (bf16_t*)(ws + OFF_W1CT);
    int tid = blockIdx.x * blockDim.x + threadIdx.x;
    int nt = gridDim.x * blockDim.x;
    for (int i = tid; i < K1 * GNN_H; i += nt) {
        int n = i / K1, k = i - n * K1;
        w1t[i] = (bf16_t)W1[k * GNN_H + n];
    }
    for (int i = tid; i < K2 * GNN_H; i += nt) {
        int n = i / K2, k = i - n * K2;
        w2t[i] = (bf16_t)W2[k * GNN_H + n];
    }
    for (int i = tid; i < 256 * 128; i += nt) {
        int n = i >> 7, k = i & 127;
        int kk = (n < 128) ? k : k + 128;
        w1abt[i] = (bf16_t)W1[kk * GNN_H + (n & 127)];
    }
    for (int i = tid; i < 128 * 64; i += nt) {
        int n = i >> 6, k = i & 63;
        w1ct[i] = (bf16_t)W1[(256 + k) * GNN_H + n];
    }
    if (blockIdx.x == 0) {
        __shared__ int any_nonzero;
        if (threadIdx.x == 0) any_nonzero = 0;
        __syncthreads();
        if (ei32[2 * threadIdx.x + 1] != 0) atomicOr(&any_nonzero, 1);
        __syncthreads();
        if (threadIdx.x == 0) *(int*)(ws + OFF_FLAG) = (any_nonzero == 0) ? 1 : 0;
    }
}

// ---------------- sort (counting sort by col) ----------------

__global__ void hist_kernel(const void* __restrict__ ei, const char* __restrict__ ws,
                            int* __restrict__ cnt) {
    int is64 = *(const int*)(ws + OFF_FLAG);
    int e = blockIdx.x * blockDim.x + threadIdx.x;
    if (e < E_EDGES) {
        long c = load_idx(ei, is64, (long)E_EDGES + e);
        atomicAdd(cnt + c, 1);
    }
}

__global__ __launch_bounds__(1024) void scan_kernel(const int* __restrict__ cnt,
                                                    int* __restrict__ rowptr,
                                                    int* __restrict__ woff) {
    __shared__ int part[1024];
    int t = threadIdx.x;
    const int CH = (NN + 1023) / 1024;
    int base = t * CH;
    int n = NN - base;
    if (n < 0) n = 0;
    if (n > CH) n = CH;
    int s = 0;
    for (int i = 0; i < n; ++i) s += cnt[base + i];
    part[t] = s;
    __syncthreads();
    for (int off = 1; off < 1024; off <<= 1) {
        int v = (t >= off) ? part[t - off] : 0;
        __syncthreads();
        part[t] += v;
        __syncthreads();
    }
    int run = part[t] - s;
    for (int i = 0; i < n; ++i) {
        rowptr[base + i] = run;
        woff[base + i] = run;
        run += cnt[base + i];
    }
    if (t == 1023) rowptr[NN] = part[1023];
}

__global__ void scatter_kernel(const void* __restrict__ ei, const char* __restrict__ ws,
                               int* __restrict__ woff, unsigned* __restrict__ perm) {
    int is64 = *(const int*)(ws + OFF_FLAG);
    int e = blockIdx.x * blockDim.x + threadIdx.x;
    if (e < E_EDGES) {
        long c = load_idx(ei, is64, (long)E_EDGES + e);
        int pos = atomicAdd(woff + c, 1);
        perm[pos] = (unsigned)e;
    }
}

// ---------------- v3: RC = x @ [W1a | W1b] (bf16 out) ----------------

__global__ __launch_bounds__(256) void rc_kernel(const float* __restrict__ x,
                                                 char* __restrict__ ws) {
    const bf16_t* w1abt = (const bf16_t*)(ws + OFF_W1ABT);
    bf16_t* rc = (bf16_t*)(ws + OFF_RC);
    int lane = threadIdx.x & 63;
    int w = threadIdx.x >> 6;
    int li = lane & 15;
    int h = lane >> 4;
    int m0 = blockIdx.x * 16;

    bf16x8 bf[4][4];
#pragma unroll
    for (int t = 0; t < 4; ++t)
#pragma unroll
        for (int ks = 0; ks < 4; ++ks)
            bf[t][ks] = *(const bf16x8*)(w1abt + (w * 64 + t * 16 + li) * 128 + ks * 32 + h * 8);

    const float* px = x + (long)(m0 + li) * NODE_H + h * 8;
    floatx4 acc[4] = {{0.f, 0.f, 0.f, 0.f}, {0.f, 0.f, 0.f, 0.f},
                      {0.f, 0.f, 0.f, 0.f}, {0.f, 0.f, 0.f, 0.f}};
#pragma unroll
    for (int ks = 0; ks < 4; ++ks) {
        floatx4 f0 = *(const floatx4*)(px + ks * 32);
        floatx4 f1 = *(const floatx4*)(px + ks * 32 + 4);
        bf16x8 a;
#pragma unroll
        for (int j = 0; j < 4; ++j) {
            a[j] = (bf16_t)f0[j];
            a[j + 4] = (bf16_t)f1[j];
        }
#pragma unroll
        for (int t = 0; t < 4; ++t) acc[t] = MFMA(a, bf[t][ks], acc[t]);
    }
#pragma unroll
    for (int t = 0; t < 4; ++t)
#pragma unroll
        for (int r = 0; r < 4; ++r)
            rc[(long)(m0 + 4 * h + r) * 256 + w * 64 + t * 16 + li] = (bf16_t)acc[t][r];
}

// ---------------- v3: fused edge (ea@W1c + R[row] + C[col]) + mean + node MLP ----
__global__ __launch_bounds__(256) void fused_v3(
    const float* __restrict__ x, const void* __restrict__ ei,
    const float* __restrict__ ea, const float* __restrict__ b1,
    const float* __restrict__ b2, const char* __restrict__ ws,
    float* __restrict__ out) {
    const bf16_t* w1ct = (const bf16_t*)(ws + OFF_W1CT);
    const bf16_t* w2t = (const bf16_t*)(ws + OFF_W2T);
    const bf16_t* rc = (const bf16_t*)(ws + OFF_RC);
    const int* rowptr = (const int*)(ws + OFF_RP);
    const int* cnt = (const int*)(ws + OFF_CNT);
    const unsigned* perm = (const unsigned*)(ws + OFF_PERM);
    int is64 = *(const int*)(ws + OFF_FLAG);

    __shared__ float agg[NB][132];
    __shared__ float cl[NB][128];  // C-part (x[col]@W1b) for the block's nodes

    int lane = threadIdx.x & 63;
    int w = threadIdx.x >> 6;
    int li = lane & 15;
    int h = lane >> 4;
    int n0 = w * 32;
    int v0 = blockIdx.x * NB;

    for (int i = threadIdx.x; i < NB * 132; i += 256) ((float*)agg)[i] = 0.f;
    {   // stage C rows for block's 16 nodes: bf16 -> f32 LDS
        int j = threadIdx.x >> 4;
        int c0 = (threadIdx.x & 15) * 8;
        bf16x8 v = *(const bf16x8*)(rc + (long)(v0 + j) * 256 + 128 + c0);
#pragma unroll
        for (int q = 0; q < 8; ++q) cl[j][c0 + q] = (float)v[q];
    }

    bf16x8 bc[2][2];
#pragma unroll
    for (int t = 0; t < 2; ++t)
#pragma unroll
        for (int ks = 0; ks < 2; ++ks)
            bc[t][ks] = *(const bf16x8*)(w1ct + (n0 + t * 16 + li) * 64 + ks * 32 + h * 8);
    float bias0 = b1[n0 + li];
    float bias1 = b1[n0 + 16 + li];

    int e_beg = rowptr[v0];
    int e_end = rowptr[v0 + NB];
    __syncthreads();

    unsigned ep = 0;
    int rowi = 0, coli = v0;
    if (e_beg < e_end) {
        int e = e_beg + li;
        int ec = e < e_end ? e : e_end - 1;
        ep = perm[ec];
        rowi = (int)load_idx(ei, is64, ep);
        coli = (int)load_idx(ei, is64, (long)E_EDGES + ep);
    }

    for (int e0 = e_beg; e0 < e_end; e0 += 16) {
        unsigned ep_c = ep;
        int rowi_c = rowi, coli_c = coli;
        if (e0 + 16 < e_end) {  // prefetch next tile's indices
            int e = e0 + 16 + li;
            int ec = e < e_end ? e : e_end - 1;
            ep = perm[ec];
            rowi = (int)load_idx(ei, is64, ep);
            coli = (int)load_idx(ei, is64, (long)E_EDGES + ep);
        }
        int nl = coli_c - v0;
        const float* pe = ea + (long)ep_c * EDGE_H + h * 8;
        floatx4 acc0 = {0.f, 0.f, 0.f, 0.f};
        floatx4 acc1 = {0.f, 0.f, 0.f, 0.f};
#pragma unroll
        for (int ks = 0; ks < 2; ++ks) {
            floatx4 f0 = *(const floatx4*)(pe + ks * 32);
            floatx4 f1 = *(const floatx4*)(pe + ks * 32 + 4);
            bf16x8 a;
#pragma unroll
            for (int j = 0; j < 4; ++j) {
                a[j] = (bf16_t)f0[j];
                a[j + 4] = (bf16_t)f1[j];
            }
            acc0 = MFMA(a, bc[0][ks], acc0);
            acc1 = MFMA(a, bc[1][ks], acc1);
        }
        // Epilogue: row r of C-frag = edge e0+4h+r. Add R[row], C[col], bias; relu.
        float m0v[4], m1v[4];
        int nlrv[4], valid[4];
#pragma unroll
        for (int r = 0; r < 4; ++r) {
            int er = e0 + h * 4 + r;
            int rowr = __shfl(rowi_c, h * 4 + r, 64);
            nlrv[r] = __shfl(nl, h * 4 + r, 64);
            valid[r] = er < e_end;
            float R0 = 0.f, R1 = 0.f;
            if (valid[r]) {
                R0 = (float)rc[(long)rowr * 256 + n0 + li];
                R1 = (float)rc[(long)rowr * 256 + n0 + 16 + li];
            }
            m0v[r] = fmaxf(acc0[r] + R0 + cl[nlrv[r]][n0 + li] + bias0, 0.f);
            m1v[r] = fmaxf(acc1[r] + R1 + cl[nlrv[r]][n0 + 16 + li] + bias1, 0.f);
        }
        if (valid[3] && nlrv[0] == nlrv[1] && nlrv[1] == nlrv[2] && nlrv[2] == nlrv[3]) {
            // common case: all 4 rows target one node -> single atomic
            atomicAdd(&agg[nlrv[0]][n0 + li], m0v[0] + m0v[1] + m0v[2] + m0v[3]);
            atomicAdd(&agg[nlrv[0]][n0 + 16 + li], m1v[0] + m1v[1] + m1v[2] + m1v[3]);
        } else {
#pragma unroll
            for (int r = 0; r < 4; ++r) {
                if (valid[r]) {
                    atomicAdd(&agg[nlrv[r]][n0 + li], m0v[r]);
                    atomicAdd(&agg[nlrv[r]][n0 + 16 + li], m1v[r]);
                }
            }
        }
    }
    __syncthreads();

    // Node MLP: out = relu([x, agg/cnt] @ W2 + b2)
    bf16x8 bfr2[2][8];
#pragma unroll
    for (int t = 0; t < 2; ++t)
#pragma unroll
        for (int ks = 0; ks < 8; ++ks)
            bfr2[t][ks] = *(const bf16x8*)(w2t + (long)(n0 + t * 16 + li) * K2 + ks * 32 + h * 8);
    float nb0 = b2[n0 + li];
    float nb1 = b2[n0 + 16 + li];

    int node = v0 + li;
    float rcn = 1.0f / fmaxf((float)cnt[node], 1.0f);
    const float* px = x + (long)node * NODE_H + h * 8;
    floatx4 acc0 = {0.f, 0.f, 0.f, 0.f};
    floatx4 acc1 = {0.f, 0.f, 0.f, 0.f};
#pragma unroll
    for (int ks = 0; ks < 8; ++ks) {
        floatx4 f0, f1;
        if (ks < 4) {
            f0 = *(const floatx4*)(px + ks * 32);
            f1 = *(const floatx4*)(px + ks * 32 + 4);
        } else {
            const float* sa = &agg[li][(ks - 4) * 32 + h * 8];
            f0 = *(const floatx4*)(sa);
            f1 = *(const floatx4*)(sa + 4);
            f0 *= rcn;
            f1 *= rcn;
        }
        bf16x8 a;
#pragma unroll
        for (int j = 0; j < 4; ++j) {
            a[j] = (bf16_t)f0[j];
            a[j + 4] = (bf16_t)f1[j];
        }
        acc0 = MFMA(a, bfr2[0][ks], acc0);
        acc1 = MFMA(a, bfr2[1][ks], acc1);
    }
#pragma unroll
    for (int r = 0; r < 4; ++r) {
        long ir = v0 + h * 4 + r;
        out[ir * GNN_H + n0 + li] = fmaxf(acc0[r] + nb0, 0.f);
        out[ir * GNN_H + n0 + 16 + li] = fmaxf(acc1[r] + nb1, 0.f);
    }
}

// ---------------- v2 fused (middle tier: sorted, full K=320) ----------------
__global__ __launch_bounds__(256) void fused_v2(
    const float* __restrict__ x, const void* __restrict__ ei,
    const float* __restrict__ ea, const float* __restrict__ b1,
    const float* __restrict__ b2, const char* __restrict__ ws,
    float* __restrict__ out) {
    const bf16_t* w1t = (const bf16_t*)(ws + OFF_W1T);
    const bf16_t* w2t = (const bf16_t*)(ws + OFF_W2T);
    const int* rowptr = (const int*)(ws + OFF_RP);
    const int* cnt = (const int*)(ws + OFF_CNT);
    const unsigned* perm = (const unsigned*)(ws + OFF_PERM);
    int is64 = *(const int*)(ws + OFF_FLAG);

    __shared__ float agg[NB][132];

    int lane = threadIdx.x & 63;
    int w = threadIdx.x >> 6;
    int li = lane & 15;
    int h = lane >> 4;
    int n0 = w * 32;
    int v0 = blockIdx.x * NB;

    for (int i = threadIdx.x; i < NB * 132; i += 256) ((float*)agg)[i] = 0.f;

    bf16x8 bfr[2][10];
#pragma unroll
    for (int t = 0; t < 2; ++t)
#pragma unroll
        for (int ks = 0; ks < 10; ++ks)
            bfr[t][ks] = *(const bf16x8*)(w1t + (long)(n0 + t * 16 + li) * K1 + ks * 32 + h * 8);
    float bias0 = b1[n0 + li];
    float bias1 = b1[n0 + 16 + li];

    int e_beg = rowptr[v0];
    int e_end = rowptr[v0 + NB];
    __syncthreads();

    unsigned ep = 0;
    long rowi = 0;
    int coli = v0;
    if (e_beg < e_end) {
        int e = e_beg + li;
        int ec = e < e_end ? e : e_end - 1;
        ep = perm[ec];
        rowi = load_idx(ei, is64, ep);
        coli = (int)load_idx(ei, is64, (long)E_EDGES + ep);
    }

    for (int e0 = e_beg; e0 < e_end; e0 += 16) {
        unsigned ep_c = ep;
        long rowi_c = rowi;
        int coli_c = coli;
        if (e0 + 16 < e_end) {
            int e = e0 + 16 + li;
            int ec = e < e_end ? e : e_end - 1;
            ep = perm[ec];
            rowi = load_idx(ei, is64, ep);
            coli = (int)load_idx(ei, is64, (long)E_EDGES + ep);
        }
        int nl = coli_c - v0;
        const float* pr = x + rowi_c * NODE_H + h * 8;
        const float* pc = x + (long)coli_c * NODE_H + h * 8;
        const float* pe = ea + (long)ep_c * EDGE_H + h * 8;
        floatx4 acc0 = {0.f, 0.f, 0.f, 0.f};
        floatx4 acc1 = {0.f, 0.f, 0.f, 0.f};
#pragma unroll
        for (int ks = 0; ks < 10; ++ks) {
            const float* src = (ks < 4) ? (pr + ks * 32) : (ks < 8) ? (pc + (ks - 4) * 32)
                                                                    : (pe + (ks - 8) * 32);
            floatx4 f0 = *(const floatx4*)(src);
            floatx4 f1 = *(const floatx4*)(src + 4);
            bf16x8 a;
#pragma unroll
            for (int j = 0; j < 4; ++j) {
                a[j] = (bf16_t)f0[j];
                a[j + 4] = (bf16_t)f1[j];
            }
            acc0 = MFMA(a, bfr[0][ks], acc0);
            acc1 = MFMA(a, bfr[1][ks], acc1);
        }
#pragma unroll
        for (int r = 0; r < 4; ++r) {
            int er = e0 + h * 4 + r;
            int nlr = __shfl(nl, h * 4 + r, 64);
            if (er < e_end) {
                float m0 = fmaxf(acc0[r] + bias0, 0.f);
                float m1 = fmaxf(acc1[r] + bias1, 0.f);
                atomicAdd(&agg[nlr][n0 + li], m0);
                atomicAdd(&agg[nlr][n0 + 16 + li], m1);
            }
        }
    }
    __syncthreads();

    bf16x8 bfr2[2][8];
#pragma unroll
    for (int t = 0; t < 2; ++t)
#pragma unroll
        for (int ks = 0; ks < 8; ++ks)
            bfr2[t][ks] = *(const bf16x8*)(w2t + (long)(n0 + t * 16 + li) * K2 + ks * 32 + h * 8);
    float nb0 = b2[n0 + li];
    float nb1 = b2[n0 + 16 + li];

    int node = v0 + li;
    float rcn = 1.0f / fmaxf((float)cnt[node], 1.0f);
    const float* px = x + (long)node * NODE_H + h * 8;
    floatx4 acc0 = {0.f, 0.f, 0.f, 0.f};
    floatx4 acc1 = {0.f, 0.f, 0.f, 0.f};
#pragma unroll
    for (int ks = 0; ks < 8; ++ks) {
        floatx4 f0, f1;
        if (ks < 4) {
            f0 = *(const floatx4*)(px + ks * 32);
            f1 = *(const floatx4*)(px + ks * 32 + 4);
        } else {
            const float* sa = &agg[li][(ks - 4) * 32 + h * 8];
            f0 = *(const floatx4*)(sa);
            f1 = *(const floatx4*)(sa + 4);
            f0 *= rcn;
            f1 *= rcn;
        }
        bf16x8 a;
#pragma unroll
        for (int j = 0; j < 4; ++j) {
            a[j] = (bf16_t)f0[j];
            a[j + 4] = (bf16_t)f1[j];
        }
        acc0 = MFMA(a, bfr2[0][ks], acc0);
        acc1 = MFMA(a, bfr2[1][ks], acc1);
    }
#pragma unroll
    for (int r = 0; r < 4; ++r) {
        long ir = v0 + h * 4 + r;
        out[ir * GNN_H + n0 + li] = fmaxf(acc0[r] + nb0, 0.f);
        out[ir * GNN_H + n0 + 16 + li] = fmaxf(acc1[r] + nb1, 0.f);
    }
}

// ---------------- v1 fallback (tiny ws; s == out in-place) ----------------

__global__ void count_kernel(const void* __restrict__ ei, const char* __restrict__ ws,
                             float* __restrict__ cnt) {
    int is64 = *(const int*)(ws + OFF_FLAG);
    int e = blockIdx.x * blockDim.x + threadIdx.x;
    if (e < E_EDGES) {
        long c = load_idx(ei, is64, (long)E_EDGES + e);
        atomicAdd(cnt + c, 1.0f);
    }
}

__global__ __launch_bounds__(256) void edge_kernel(
    const float* __restrict__ x, const void* __restrict__ ei,
    const float* __restrict__ ea, const float* __restrict__ b1,
    const char* __restrict__ ws, float* __restrict__ s) {
    const bf16_t* w1t = (const bf16_t*)(ws + OFF_W1T);
    int is64 = *(const int*)(ws + OFF_FLAG);
    int lane = threadIdx.x & 63;
    int w = threadIdx.x >> 6;
    int li = lane & 15;
    int h = lane >> 4;
    int n0 = w * 32;

    bf16x8 bf[2][10];
#pragma unroll
    for (int t = 0; t < 2; ++t)
#pragma unroll
        for (int ks = 0; ks < 10; ++ks)
            bf[t][ks] = *(const bf16x8*)(w1t + (long)(n0 + t * 16 + li) * K1 + ks * 32 + h * 8);
    float bias0 = b1[n0 + li];
    float bias1 = b1[n0 + 16 + li];

    const int ntiles = E_EDGES / 16;
    for (int tile = blockIdx.x; tile < ntiles; tile += gridDim.x) {
        int m0 = tile * 16;
        int e = m0 + li;
        long rowi = load_idx(ei, is64, e);
        long coli = load_idx(ei, is64, (long)E_EDGES + e);
        const float* pr = x + rowi * NODE_H + h * 8;
        const float* pc = x + coli * NODE_H + h * 8;
        const float* pe = ea + (long)e * EDGE_H + h * 8;
        floatx4 acc0 = {0.f, 0.f, 0.f, 0.f};
        floatx4 acc1 = {0.f, 0.f, 0.f, 0.f};
#pragma unroll
        for (int ks = 0; ks < 10; ++ks) {
            const float* src = (ks < 4) ? (pr + ks * 32) : (ks < 8) ? (pc + (ks - 4) * 32)
                                                                    : (pe + (ks - 8) * 32);
            floatx4 f0 = *(const floatx4*)(src);
            floatx4 f1 = *(const floatx4*)(src + 4);
            bf16x8 a;
#pragma unroll
            for (int j = 0; j < 4; ++j) {
                a[j] = (bf16_t)f0[j];
                a[j + 4] = (bf16_t)f1[j];
            }
            acc0 = MFMA(a, bf[0][ks], acc0);
            acc1 = MFMA(a, bf[1][ks], acc1);
        }
        long cols[4];
#pragma unroll
        for (int r = 0; r < 4; ++r)
            cols[r] = load_idx(ei, is64, (long)E_EDGES + m0 + h * 4 + r);
#pragma unroll
        for (int r = 0; r < 4; ++r) {
            float v0 = fmaxf(acc0[r] + bias0, 0.f);
            float v1 = fmaxf(acc1[r] + bias1, 0.f);
            atomicAdd(s + cols[r] * GNN_H + n0 + li, v0);
            atomicAdd(s + cols[r] * GNN_H + n0 + 16 + li, v1);
        }
    }
}

__global__ __launch_bounds__(256) void node_kernel(
    const float* __restrict__ x, const float* __restrict__ b2,
    const char* __restrict__ ws, const float* __restrict__ cnt,
    const float* __restrict__ s, float* __restrict__ out) {
    const bf16_t* w2t = (const bf16_t*)(ws + OFF_W2T);
    int lane = threadIdx.x & 63;
    int w = threadIdx.x >> 6;
    int li = lane & 15;
    int h = lane >> 4;
    int n0 = w * 32;

    bf16x8 bf[2][8];
#pragma unroll
    for (int t = 0; t < 2; ++t)
#pragma unroll
        for (int ks = 0; ks < 8; ++ks)
            bf[t][ks] = *(const bf16x8*)(w2t + (long)(n0 + t * 16 + li) * K2 + ks * 32 + h * 8);
    float bias0 = b2[n0 + li];
    float bias1 = b2[n0 + 16 + li];

    int m0 = blockIdx.x * 16;
    int i = m0 + li;
    float rcn = 1.0f / fmaxf(cnt[i], 1.0f);
    const float* px = x + (long)i * NODE_H + h * 8;
    const float* ps = s + (long)i * GNN_H + h * 8;
    floatx4 acc0 = {0.f, 0.f, 0.f, 0.f};
    floatx4 acc1 = {0.f, 0.f, 0.f, 0.f};
#pragma unroll
    for (int ks = 0; ks < 8; ++ks) {
        const float* src = (ks < 4) ? (px + ks * 32) : (ps + (ks - 4) * 32);
        floatx4 f0 = *(const floatx4*)(src);
        floatx4 f1 = *(const floatx4*)(src + 4);
        if (ks >= 4) {
            f0 *= rcn;
            f1 *= rcn;
        }
        bf16x8 a;
#pragma unroll
        for (int j = 0; j < 4; ++j) {
            a[j] = (bf16_t)f0[j];
            a[j + 4] = (bf16_t)f1[j];
        }
        acc0 = MFMA(a, bf[0][ks], acc0);
        acc1 = MFMA(a, bf[1][ks], acc1);
    }
    __syncthreads();  // s == out in-place: all reads done before stores
#pragma unroll
    for (int r = 0; r < 4; ++r) {
        long ir = m0 + h * 4 + r;
        out[ir * GNN_H + n0 + li] = fmaxf(acc0[r] + bias0, 0.f);
        out[ir * GNN_H + n0 + 16 + li] = fmaxf(acc1[r] + bias1, 0.f);
    }
}

extern "C" void kernel_launch(void* const* d_in, const int* in_sizes, int n_in,
                              void* d_out, int out_size, void* d_ws, size_t ws_size,
                              hipStream_t stream) {
    const float* x = (const float*)d_in[0];
    const void* ei = d_in[1];
    const float* ea = (const float*)d_in[2];
    const float* W1 = (const float*)d_in[3];
    const float* b1 = (const float*)d_in[4];
    const float* W2 = (const float*)d_in[5];
    const float* b2 = (const float*)d_in[6];
    float* out = (float*)d_out;
    char* ws = (char*)d_ws;

    prep_kernel<<<32, 256, 0, stream>>>(W1, W2, (const int*)ei, ws);

    if (ws_size >= WS_V2) {
        int* cnt = (int*)(ws + OFF_CNT);
        hipMemsetAsync(cnt, 0, NN * 4, stream);
        hist_kernel<<<E_EDGES / 256, 256, 0, stream>>>(ei, ws, cnt);
        scan_kernel<<<1, 1024, 0, stream>>>(cnt, (int*)(ws + OFF_RP), (int*)(ws + OFF_WOFF));
        scatter_kernel<<<E_EDGES / 256, 256, 0, stream>>>(ei, ws, (int*)(ws + OFF_WOFF),
                                                          (unsigned*)(ws + OFF_PERM));
        if (ws_size >= WS_V3) {
            rc_kernel<<<NN / 16, 256, 0, stream>>>(x, ws);
            fused_v3<<<NN / NB, 256, 0, stream>>>(x, ei, ea, b1, b2, ws, out);
        } else {
            fused_v2<<<NN / NB, 256, 0, stream>>>(x, ei, ea, b1, b2, ws, out);
        }
    } else {
        float* cntf = (float*)(ws + OFF_CNT);
        hipMemsetAsync(cntf, 0, NN * 4, stream);
        hipMemsetAsync(out, 0, (size_t)NN * GNN_H * 4, stream);
        count_kernel<<<E_EDGES / 256, 256, 0, stream>>>(ei, ws, cntf);
        edge_kernel<<<4096, 256, 0, stream>>>(x, ei, ea, b1, ws, out);
        node_kernel<<<NN / 16, 256, 0, stream>>>(x, b2, ws, cntf, out, out);
    }
}

// Round 4
// 578.908 us; speedup vs baseline: 1.8144x; 1.1190x over previous
//
#include <hip/hip_runtime.h>
#include <hip/hip_bf16.h>
#include <stdint.h>

// Problem constants (from reference)
#define E_EDGES 1048576
#define NN 50000
#define NODE_H 128
#define EDGE_H 64
#define GNN_H 128
#define K1 320  // 2*NODE_H + EDGE_H
#define K2 256  // NODE_H + GNN_H
#define NB 16   // nodes per block in fused kernels

typedef __bf16 bf16_t;
typedef __bf16 bf16x8 __attribute__((ext_vector_type(8)));
typedef float floatx4 __attribute__((ext_vector_type(4)));

// Workspace layout (bytes)
#define OFF_FLAG 0
#define OFF_CNT 256          // int cnt[NN]                              200192
#define OFF_W1T 200448       // bf16 W1^T [128][320]                     81920
#define OFF_W2T 282368       // bf16 W2^T [128][256]                     65536
#define OFF_W1ABT 347904     // bf16 [256][128]: n<128 -> W1a^T, else W1b^T
#define OFF_W1CT 413440      // bf16 W1c^T [128][64]                     16384
#define OFF_RP 429824        // int rowptr[NN+1]                        200448
#define OFF_WOFF 630272      // int woff[NN]                            200192
#define OFF_PERM 830464      // uint perm[E] (v3 path)                 4194304
#define OFF_RC 5024768       // bf16 RC[NN][256]: [0:128]=x@W1a, [128:256]=x@W1b
#define WS_V3 ((size_t)OFF_RC + (size_t)NN * 256 * 2)   // 30624768
#define OFF_PK64 WS_V3                                   // u64 packed[E] (v4)
#define WS_V4 (WS_V3 + (size_t)E_EDGES * 8)              // 39013376

__device__ __forceinline__ long load_idx(const void* ei, int is64, long off) {
    return is64 ? (long)((const long long*)ei)[off] : (long)((const int*)ei)[off];
}

#define MFMA(a, b, c) __builtin_amdgcn_mfma_f32_16x16x32_bf16(a, b, c, 0, 0, 0)

// Prep: weight transforms + edge_index dtype probe.
__global__ void prep_kernel(const float* __restrict__ W1, const float* __restrict__ W2,
                            const int* __restrict__ ei32, char* __restrict__ ws) {
    bf16_t* w1t = (bf16_t*)(ws + OFF_W1T);
    bf16_t* w2t = (bf16_t*)(ws + OFF_W2T);
    bf16_t* w1abt = (bf16_t*)(ws + OFF_W1ABT);
    bf16_t* w1ct = (bf16_t*)(ws + OFF_W1CT);
    int tid = blockIdx.x * blockDim.x + threadIdx.x;
    int nt = gridDim.x * blockDim.x;
    for (int i = tid; i < K1 * GNN_H; i += nt) {
        int n = i / K1, k = i - n * K1;
        w1t[i] = (bf16_t)W1[k * GNN_H + n];
    }
    for (int i = tid; i < K2 * GNN_H; i += nt) {
        int n = i / K2, k = i - n * K2;
        w2t[i] = (bf16_t)W2[k * GNN_H + n];
    }
    for (int i = tid; i < 256 * 128; i += nt) {
        int n = i >> 7, k = i & 127;
        int kk = (n < 128) ? k : k + 128;
        w1abt[i] = (bf16_t)W1[kk * GNN_H + (n & 127)];
    }
    for (int i = tid; i < 128 * 64; i += nt) {
        int n = i >> 6, k = i & 63;
        w1ct[i] = (bf16_t)W1[(256 + k) * GNN_H + n];
    }
    if (blockIdx.x == 0) {
        __shared__ int any_nonzero;
        if (threadIdx.x == 0) any_nonzero = 0;
        __syncthreads();
        if (ei32[2 * threadIdx.x + 1] != 0) atomicOr(&any_nonzero, 1);
        __syncthreads();
        if (threadIdx.x == 0) *(int*)(ws + OFF_FLAG) = (any_nonzero == 0) ? 1 : 0;
    }
}

// ---------------- counting sort by col ----------------

__global__ void hist_kernel(const void* __restrict__ ei, const char* __restrict__ ws,
                            int* __restrict__ cnt) {
    int is64 = *(const int*)(ws + OFF_FLAG);
    int e = blockIdx.x * blockDim.x + threadIdx.x;
    if (e < E_EDGES) {
        long c = load_idx(ei, is64, (long)E_EDGES + e);
        atomicAdd(cnt + c, 1);
    }
}

__global__ __launch_bounds__(1024) void scan_kernel(const int* __restrict__ cnt,
                                                    int* __restrict__ rowptr,
                                                    int* __restrict__ woff) {
    __shared__ int part[1024];
    int t = threadIdx.x;
    const int CH = (NN + 1023) / 1024;
    int base = t * CH;
    int n = NN - base;
    if (n < 0) n = 0;
    if (n > CH) n = CH;
    int s = 0;
    for (int i = 0; i < n; ++i) s += cnt[base + i];
    part[t] = s;
    __syncthreads();
    for (int off = 1; off < 1024; off <<= 1) {
        int v = (t >= off) ? part[t - off] : 0;
        __syncthreads();
        part[t] += v;
        __syncthreads();
    }
    int run = part[t] - s;
    for (int i = 0; i < n; ++i) {
        rowptr[base + i] = run;
        woff[base + i] = run;
        run += cnt[base + i];
    }
    if (t == 1023) rowptr[NN] = part[1023];
}

// mode 0: write uint32 perm (v3). mode 1: write packed u64 {e:20 | row:17<<20 | nl:4<<37}.
__global__ void scatter_kernel(const void* __restrict__ ei, const char* __restrict__ ws,
                               int* __restrict__ woff, unsigned* __restrict__ perm32,
                               unsigned long long* __restrict__ pk64, int mode) {
    int is64 = *(const int*)(ws + OFF_FLAG);
    int e = blockIdx.x * blockDim.x + threadIdx.x;
    if (e < E_EDGES) {
        long row = load_idx(ei, is64, e);
        long col = load_idx(ei, is64, (long)E_EDGES + e);
        int pos = atomicAdd(woff + col, 1);
        if (mode) {
            pk64[pos] = (unsigned long long)e |
                        ((unsigned long long)(unsigned)row << 20) |
                        ((unsigned long long)((unsigned)col & 15u) << 37);
        } else {
            perm32[pos] = (unsigned)e;
        }
    }
}

// ---------------- RC = x @ [W1a | W1b] (bf16 out) ----------------

__global__ __launch_bounds__(256) void rc_kernel(const float* __restrict__ x,
                                                 char* __restrict__ ws) {
    const bf16_t* w1abt = (const bf16_t*)(ws + OFF_W1ABT);
    bf16_t* rc = (bf16_t*)(ws + OFF_RC);
    int lane = threadIdx.x & 63;
    int w = threadIdx.x >> 6;
    int li = lane & 15;
    int h = lane >> 4;
    int m0 = blockIdx.x * 16;

    bf16x8 bf[4][4];
#pragma unroll
    for (int t = 0; t < 4; ++t)
#pragma unroll
        for (int ks = 0; ks < 4; ++ks)
            bf[t][ks] = *(const bf16x8*)(w1abt + (w * 64 + t * 16 + li) * 128 + ks * 32 + h * 8);

    const float* px = x + (long)(m0 + li) * NODE_H + h * 8;
    floatx4 acc[4] = {{0.f, 0.f, 0.f, 0.f}, {0.f, 0.f, 0.f, 0.f},
                      {0.f, 0.f, 0.f, 0.f}, {0.f, 0.f, 0.f, 0.f}};
#pragma unroll
    for (int ks = 0; ks < 4; ++ks) {
        floatx4 f0 = *(const floatx4*)(px + ks * 32);
        floatx4 f1 = *(const floatx4*)(px + ks * 32 + 4);
        bf16x8 a;
#pragma unroll
        for (int j = 0; j < 4; ++j) {
            a[j] = (bf16_t)f0[j];
            a[j + 4] = (bf16_t)f1[j];
        }
#pragma unroll
        for (int t = 0; t < 4; ++t) acc[t] = MFMA(a, bf[t][ks], acc[t]);
    }
#pragma unroll
    for (int t = 0; t < 4; ++t)
#pragma unroll
        for (int r = 0; r < 4; ++r)
            rc[(long)(m0 + 4 * h + r) * 256 + w * 64 + t * 16 + li] = (bf16_t)acc[t][r];
}

// ---------------- v4 fused: 3-stage pipelined ----------------
__global__ __launch_bounds__(256) void fused_v4(
    const float* __restrict__ x, const float* __restrict__ ea,
    const float* __restrict__ b1, const float* __restrict__ b2,
    const char* __restrict__ ws, float* __restrict__ out) {
    const bf16_t* w1ct = (const bf16_t*)(ws + OFF_W1CT);
    const bf16_t* w2t = (const bf16_t*)(ws + OFF_W2T);
    const bf16_t* rc = (const bf16_t*)(ws + OFF_RC);
    const int* rowptr = (const int*)(ws + OFF_RP);
    const unsigned long long* pk64 = (const unsigned long long*)(ws + OFF_PK64);

    __shared__ float agg[NB][132];
    __shared__ float cl[NB][128];

    int lane = threadIdx.x & 63;
    int w = threadIdx.x >> 6;
    int li = lane & 15;
    int h = lane >> 4;
    int n0 = w * 32;
    int v0 = blockIdx.x * NB;

    for (int i = threadIdx.x; i < NB * 132; i += 256) ((float*)agg)[i] = 0.f;
    {   // stage C-part rows for the block's 16 nodes
        int j = threadIdx.x >> 4;
        int c0 = (threadIdx.x & 15) * 8;
        bf16x8 v = *(const bf16x8*)(rc + (long)(v0 + j) * 256 + 128 + c0);
#pragma unroll
        for (int q = 0; q < 8; ++q) cl[j][c0 + q] = (float)v[q];
    }

    bf16x8 bc00 = *(const bf16x8*)(w1ct + (n0 + li) * 64 + h * 8);
    bf16x8 bc01 = *(const bf16x8*)(w1ct + (n0 + li) * 64 + 32 + h * 8);
    bf16x8 bc10 = *(const bf16x8*)(w1ct + (n0 + 16 + li) * 64 + h * 8);
    bf16x8 bc11 = *(const bf16x8*)(w1ct + (n0 + 16 + li) * 64 + 32 + h * 8);
    float bias0 = b1[n0 + li];
    float bias1 = b1[n0 + 16 + li];

    int e_beg = rowptr[v0];
    int e_end = rowptr[v0 + NB];
    __syncthreads();

    if (e_beg < e_end) {
        int ntile = (e_end - e_beg + 15) >> 4;
        auto posOf = [&](int t) { int p = e_beg + (t << 4) + li; return p < e_end ? p : e_end - 1; };

        // ---- prologue: tile 0 state + tile 1 packed in flight ----
        unsigned long long pkA = pk64[posOf(0)];
        unsigned long long pkB = pk64[posOf(ntile > 1 ? 1 : 0)];
        unsigned eA = (unsigned)pkA & 0xFFFFFu;
        const float* peA = ea + (size_t)eA * EDGE_H + h * 8;
        floatx4 eaA00 = *(const floatx4*)peA;
        floatx4 eaA01 = *(const floatx4*)(peA + 4);
        floatx4 eaA10 = *(const floatx4*)(peA + 32);
        floatx4 eaA11 = *(const floatx4*)(peA + 36);
        int rowA = (int)((pkA >> 20) & 0x1FFFFu);
        int nlA = (int)((pkA >> 37) & 15u);
        bf16_t RA0[4], RA1[4];
        int nlrA[4];
#pragma unroll
        for (int r = 0; r < 4; ++r) {
            int rr = __shfl(rowA, h * 4 + r, 64);
            nlrA[r] = __shfl(nlA, h * 4 + r, 64);
            const bf16_t* pr = rc + (size_t)rr * 256 + n0 + li;
            RA0[r] = pr[0];
            RA1[r] = pr[16];
        }

        for (int t = 0; t < ntile; ++t) {
            // ---- issue loads for t+2 (packed) and t+1 (ea, R) ----
            unsigned long long pkC = pk64[posOf(t + 2 < ntile ? t + 2 : ntile - 1)];
            unsigned eB = (unsigned)pkB & 0xFFFFFu;
            const float* peB = ea + (size_t)eB * EDGE_H + h * 8;
            floatx4 eaB00 = *(const floatx4*)peB;
            floatx4 eaB01 = *(const floatx4*)(peB + 4);
            floatx4 eaB10 = *(const floatx4*)(peB + 32);
            floatx4 eaB11 = *(const floatx4*)(peB + 36);
            int rowB = (int)((pkB >> 20) & 0x1FFFFu);
            int nlB = (int)((pkB >> 37) & 15u);
            bf16_t RB0[4], RB1[4];
            int nlrB[4];
#pragma unroll
            for (int r = 0; r < 4; ++r) {
                int rr = __shfl(rowB, h * 4 + r, 64);
                nlrB[r] = __shfl(nlB, h * 4 + r, 64);
                const bf16_t* pr = rc + (size_t)rr * 256 + n0 + li;
                RB0[r] = pr[0];
                RB1[r] = pr[16];
            }

            // ---- compute tile t (all operands arrived during t-1) ----
            bf16x8 a0, a1;
#pragma unroll
            for (int j = 0; j < 4; ++j) {
                a0[j] = (bf16_t)eaA00[j];
                a0[j + 4] = (bf16_t)eaA01[j];
                a1[j] = (bf16_t)eaA10[j];
                a1[j + 4] = (bf16_t)eaA11[j];
            }
            floatx4 acc0 = {0.f, 0.f, 0.f, 0.f};
            floatx4 acc1 = {0.f, 0.f, 0.f, 0.f};
            acc0 = MFMA(a0, bc00, acc0);
            acc0 = MFMA(a1, bc01, acc0);
            acc1 = MFMA(a0, bc10, acc1);
            acc1 = MFMA(a1, bc11, acc1);

            int base = e_beg + (t << 4);
            float m0v[4], m1v[4];
            int valid[4];
#pragma unroll
            for (int r = 0; r < 4; ++r) {
                valid[r] = (base + h * 4 + r) < e_end;
                m0v[r] = fmaxf(acc0[r] + (float)RA0[r] + cl[nlrA[r]][n0 + li] + bias0, 0.f);
                m1v[r] = fmaxf(acc1[r] + (float)RA1[r] + cl[nlrA[r]][n0 + 16 + li] + bias1, 0.f);
            }
            if (valid[3] && nlrA[0] == nlrA[1] && nlrA[1] == nlrA[2] && nlrA[2] == nlrA[3]) {
                atomicAdd(&agg[nlrA[0]][n0 + li], m0v[0] + m0v[1] + m0v[2] + m0v[3]);
                atomicAdd(&agg[nlrA[0]][n0 + 16 + li], m1v[0] + m1v[1] + m1v[2] + m1v[3]);
            } else {
#pragma unroll
                for (int r = 0; r < 4; ++r) {
                    if (valid[r]) {
                        atomicAdd(&agg[nlrA[r]][n0 + li], m0v[r]);
                        atomicAdd(&agg[nlrA[r]][n0 + 16 + li], m1v[r]);
                    }
                }
            }
            // ---- rotate pipeline registers ----
            pkA = pkB;
            pkB = pkC;
            eaA00 = eaB00; eaA01 = eaB01; eaA10 = eaB10; eaA11 = eaB11;
#pragma unroll
            for (int r = 0; r < 4; ++r) {
                RA0[r] = RB0[r];
                RA1[r] = RB1[r];
                nlrA[r] = nlrB[r];
            }
        }
    }
    __syncthreads();

    // ---- node MLP: out = relu([x, agg/cnt] @ W2 + b2) ----
    bf16x8 bfr2[2][8];
#pragma unroll
    for (int t = 0; t < 2; ++t)
#pragma unroll
        for (int ks = 0; ks < 8; ++ks)
            bfr2[t][ks] = *(const bf16x8*)(w2t + (long)(n0 + t * 16 + li) * K2 + ks * 32 + h * 8);
    float nb0 = b2[n0 + li];
    float nb1 = b2[n0 + 16 + li];

    int node = v0 + li;
    int c0n = rowptr[node];
    int c1n = rowptr[node + 1];
    float rcn = 1.0f / fmaxf((float)(c1n - c0n), 1.0f);
    const float* px = x + (long)node * NODE_H + h * 8;
    floatx4 acc0 = {0.f, 0.f, 0.f, 0.f};
    floatx4 acc1 = {0.f, 0.f, 0.f, 0.f};
#pragma unroll
    for (int ks = 0; ks < 8; ++ks) {
        floatx4 f0, f1;
        if (ks < 4) {
            f0 = *(const floatx4*)(px + ks * 32);
            f1 = *(const floatx4*)(px + ks * 32 + 4);
        } else {
            const float* sa = &agg[li][(ks - 4) * 32 + h * 8];
            f0 = *(const floatx4*)(sa);
            f1 = *(const floatx4*)(sa + 4);
            f0 *= rcn;
            f1 *= rcn;
        }
        bf16x8 a;
#pragma unroll
        for (int j = 0; j < 4; ++j) {
            a[j] = (bf16_t)f0[j];
            a[j + 4] = (bf16_t)f1[j];
        }
        acc0 = MFMA(a, bfr2[0][ks], acc0);
        acc1 = MFMA(a, bfr2[1][ks], acc1);
    }
#pragma unroll
    for (int r = 0; r < 4; ++r) {
        long ir = v0 + h * 4 + r;
        out[ir * GNN_H + n0 + li] = fmaxf(acc0[r] + nb0, 0.f);
        out[ir * GNN_H + n0 + 16 + li] = fmaxf(acc1[r] + nb1, 0.f);
    }
}

// ---------------- v3 fused (fallback: ws in [30.6, 39) MB) ----------------
__global__ __launch_bounds__(256) void fused_v3(
    const float* __restrict__ x, const void* __restrict__ ei,
    const float* __restrict__ ea, const float* __restrict__ b1,
    const float* __restrict__ b2, const char* __restrict__ ws,
    float* __restrict__ out) {
    const bf16_t* w1ct = (const bf16_t*)(ws + OFF_W1CT);
    const bf16_t* w2t = (const bf16_t*)(ws + OFF_W2T);
    const bf16_t* rc = (const bf16_t*)(ws + OFF_RC);
    const int* rowptr = (const int*)(ws + OFF_RP);
    const int* cnt = (const int*)(ws + OFF_CNT);
    const unsigned* perm = (const unsigned*)(ws + OFF_PERM);
    int is64 = *(const int*)(ws + OFF_FLAG);

    __shared__ float agg[NB][132];
    __shared__ float cl[NB][128];

    int lane = threadIdx.x & 63;
    int w = threadIdx.x >> 6;
    int li = lane & 15;
    int h = lane >> 4;
    int n0 = w * 32;
    int v0 = blockIdx.x * NB;

    for (int i = threadIdx.x; i < NB * 132; i += 256) ((float*)agg)[i] = 0.f;
    {
        int j = threadIdx.x >> 4;
        int c0 = (threadIdx.x & 15) * 8;
        bf16x8 v = *(const bf16x8*)(rc + (long)(v0 + j) * 256 + 128 + c0);
#pragma unroll
        for (int q = 0; q < 8; ++q) cl[j][c0 + q] = (float)v[q];
    }

    bf16x8 bc[2][2];
#pragma unroll
    for (int t = 0; t < 2; ++t)
#pragma unroll
        for (int ks = 0; ks < 2; ++ks)
            bc[t][ks] = *(const bf16x8*)(w1ct + (n0 + t * 16 + li) * 64 + ks * 32 + h * 8);
    float bias0 = b1[n0 + li];
    float bias1 = b1[n0 + 16 + li];

    int e_beg = rowptr[v0];
    int e_end = rowptr[v0 + NB];
    __syncthreads();

    unsigned ep = 0;
    int rowi = 0, coli = v0;
    if (e_beg < e_end) {
        int e = e_beg + li;
        int ec = e < e_end ? e : e_end - 1;
        ep = perm[ec];
        rowi = (int)load_idx(ei, is64, ep);
        coli = (int)load_idx(ei, is64, (long)E_EDGES + ep);
    }

    for (int e0 = e_beg; e0 < e_end; e0 += 16) {
        unsigned ep_c = ep;
        int rowi_c = rowi, coli_c = coli;
        if (e0 + 16 < e_end) {
            int e = e0 + 16 + li;
            int ec = e < e_end ? e : e_end - 1;
            ep = perm[ec];
            rowi = (int)load_idx(ei, is64, ep);
            coli = (int)load_idx(ei, is64, (long)E_EDGES + ep);
        }
        int nl = coli_c - v0;
        const float* pe = ea + (long)ep_c * EDGE_H + h * 8;
        floatx4 acc0 = {0.f, 0.f, 0.f, 0.f};
        floatx4 acc1 = {0.f, 0.f, 0.f, 0.f};
#pragma unroll
        for (int ks = 0; ks < 2; ++ks) {
            floatx4 f0 = *(const floatx4*)(pe + ks * 32);
            floatx4 f1 = *(const floatx4*)(pe + ks * 32 + 4);
            bf16x8 a;
#pragma unroll
            for (int j = 0; j < 4; ++j) {
                a[j] = (bf16_t)f0[j];
                a[j + 4] = (bf16_t)f1[j];
            }
            acc0 = MFMA(a, bc[0][ks], acc0);
            acc1 = MFMA(a, bc[1][ks], acc1);
        }
        float m0v[4], m1v[4];
        int nlrv[4], valid[4];
#pragma unroll
        for (int r = 0; r < 4; ++r) {
            int er = e0 + h * 4 + r;
            int rowr = __shfl(rowi_c, h * 4 + r, 64);
            nlrv[r] = __shfl(nl, h * 4 + r, 64);
            valid[r] = er < e_end;
            float R0 = 0.f, R1 = 0.f;
            if (valid[r]) {
                R0 = (float)rc[(long)rowr * 256 + n0 + li];
                R1 = (float)rc[(long)rowr * 256 + n0 + 16 + li];
            }
            m0v[r] = fmaxf(acc0[r] + R0 + cl[nlrv[r]][n0 + li] + bias0, 0.f);
            m1v[r] = fmaxf(acc1[r] + R1 + cl[nlrv[r]][n0 + 16 + li] + bias1, 0.f);
        }
        if (valid[3] && nlrv[0] == nlrv[1] && nlrv[1] == nlrv[2] && nlrv[2] == nlrv[3]) {
            atomicAdd(&agg[nlrv[0]][n0 + li], m0v[0] + m0v[1] + m0v[2] + m0v[3]);
            atomicAdd(&agg[nlrv[0]][n0 + 16 + li], m1v[0] + m1v[1] + m1v[2] + m1v[3]);
        } else {
#pragma unroll
            for (int r = 0; r < 4; ++r) {
                if (valid[r]) {
                    atomicAdd(&agg[nlrv[r]][n0 + li], m0v[r]);
                    atomicAdd(&agg[nlrv[r]][n0 + 16 + li], m1v[r]);
                }
            }
        }
    }
    __syncthreads();

    bf16x8 bfr2[2][8];
#pragma unroll
    for (int t = 0; t < 2; ++t)
#pragma unroll
        for (int ks = 0; ks < 8; ++ks)
            bfr2[t][ks] = *(const bf16x8*)(w2t + (long)(n0 + t * 16 + li) * K2 + ks * 32 + h * 8);
    float nb0 = b2[n0 + li];
    float nb1 = b2[n0 + 16 + li];

    int node = v0 + li;
    float rcn = 1.0f / fmaxf((float)cnt[node], 1.0f);
    const float* px = x + (long)node * NODE_H + h * 8;
    floatx4 acc0 = {0.f, 0.f, 0.f, 0.f};
    floatx4 acc1 = {0.f, 0.f, 0.f, 0.f};
#pragma unroll
    for (int ks = 0; ks < 8; ++ks) {
        floatx4 f0, f1;
        if (ks < 4) {
            f0 = *(const floatx4*)(px + ks * 32);
            f1 = *(const floatx4*)(px + ks * 32 + 4);
        } else {
            const float* sa = &agg[li][(ks - 4) * 32 + h * 8];
            f0 = *(const floatx4*)(sa);
            f1 = *(const floatx4*)(sa + 4);
            f0 *= rcn;
            f1 *= rcn;
        }
        bf16x8 a;
#pragma unroll
        for (int j = 0; j < 4; ++j) {
            a[j] = (bf16_t)f0[j];
            a[j + 4] = (bf16_t)f1[j];
        }
        acc0 = MFMA(a, bfr2[0][ks], acc0);
        acc1 = MFMA(a, bfr2[1][ks], acc1);
    }
#pragma unroll
    for (int r = 0; r < 4; ++r) {
        long ir = v0 + h * 4 + r;
        out[ir * GNN_H + n0 + li] = fmaxf(acc0[r] + nb0, 0.f);
        out[ir * GNN_H + n0 + 16 + li] = fmaxf(acc1[r] + nb1, 0.f);
    }
}

// ---------------- v1 fallback (tiny ws; s == out in-place) ----------------

__global__ void count_kernel(const void* __restrict__ ei, const char* __restrict__ ws,
                             float* __restrict__ cnt) {
    int is64 = *(const int*)(ws + OFF_FLAG);
    int e = blockIdx.x * blockDim.x + threadIdx.x;
    if (e < E_EDGES) {
        long c = load_idx(ei, is64, (long)E_EDGES + e);
        atomicAdd(cnt + c, 1.0f);
    }
}

__global__ __launch_bounds__(256) void edge_kernel(
    const float* __restrict__ x, const void* __restrict__ ei,
    const float* __restrict__ ea, const float* __restrict__ b1,
    const char* __restrict__ ws, float* __restrict__ s) {
    const bf16_t* w1t = (const bf16_t*)(ws + OFF_W1T);
    int is64 = *(const int*)(ws + OFF_FLAG);
    int lane = threadIdx.x & 63;
    int w = threadIdx.x >> 6;
    int li = lane & 15;
    int h = lane >> 4;
    int n0 = w * 32;

    bf16x8 bf[2][10];
#pragma unroll
    for (int t = 0; t < 2; ++t)
#pragma unroll
        for (int ks = 0; ks < 10; ++ks)
            bf[t][ks] = *(const bf16x8*)(w1t + (long)(n0 + t * 16 + li) * K1 + ks * 32 + h * 8);
    float bias0 = b1[n0 + li];
    float bias1 = b1[n0 + 16 + li];

    const int ntiles = E_EDGES / 16;
    for (int tile = blockIdx.x; tile < ntiles; tile += gridDim.x) {
        int m0 = tile * 16;
        int e = m0 + li;
        long rowi = load_idx(ei, is64, e);
        long coli = load_idx(ei, is64, (long)E_EDGES + e);
        const float* pr = x + rowi * NODE_H + h * 8;
        const float* pc = x + coli * NODE_H + h * 8;
        const float* pe = ea + (long)e * EDGE_H + h * 8;
        floatx4 acc0 = {0.f, 0.f, 0.f, 0.f};
        floatx4 acc1 = {0.f, 0.f, 0.f, 0.f};
#pragma unroll
        for (int ks = 0; ks < 10; ++ks) {
            const float* src = (ks < 4) ? (pr + ks * 32) : (ks < 8) ? (pc + (ks - 4) * 32)
                                                                    : (pe + (ks - 8) * 32);
            floatx4 f0 = *(const floatx4*)(src);
            floatx4 f1 = *(const floatx4*)(src + 4);
            bf16x8 a;
#pragma unroll
            for (int j = 0; j < 4; ++j) {
                a[j] = (bf16_t)f0[j];
                a[j + 4] = (bf16_t)f1[j];
            }
            acc0 = MFMA(a, bf[0][ks], acc0);
            acc1 = MFMA(a, bf[1][ks], acc1);
        }
        long cols[4];
#pragma unroll
        for (int r = 0; r < 4; ++r)
            cols[r] = load_idx(ei, is64, (long)E_EDGES + m0 + h * 4 + r);
#pragma unroll
        for (int r = 0; r < 4; ++r) {
            float v0 = fmaxf(acc0[r] + bias0, 0.f);
            float v1 = fmaxf(acc1[r] + bias1, 0.f);
            atomicAdd(s + cols[r] * GNN_H + n0 + li, v0);
            atomicAdd(s + cols[r] * GNN_H + n0 + 16 + li, v1);
        }
    }
}

__global__ __launch_bounds__(256) void node_kernel(
    const float* __restrict__ x, const float* __restrict__ b2,
    const char* __restrict__ ws, const float* __restrict__ cnt,
    const float* __restrict__ s, float* __restrict__ out) {
    const bf16_t* w2t = (const bf16_t*)(ws + OFF_W2T);
    int lane = threadIdx.x & 63;
    int w = threadIdx.x >> 6;
    int li = lane & 15;
    int h = lane >> 4;
    int n0 = w * 32;

    bf16x8 bf[2][8];
#pragma unroll
    for (int t = 0; t < 2; ++t)
#pragma unroll
        for (int ks = 0; ks < 8; ++ks)
            bf[t][ks] = *(const bf16x8*)(w2t + (long)(n0 + t * 16 + li) * K2 + ks * 32 + h * 8);
    float bias0 = b2[n0 + li];
    float bias1 = b2[n0 + 16 + li];

    int m0 = blockIdx.x * 16;
    int i = m0 + li;
    float rcn = 1.0f / fmaxf(cnt[i], 1.0f);
    const float* px = x + (long)i * NODE_H + h * 8;
    const float* ps = s + (long)i * GNN_H + h * 8;
    floatx4 acc0 = {0.f, 0.f, 0.f, 0.f};
    floatx4 acc1 = {0.f, 0.f, 0.f, 0.f};
#pragma unroll
    for (int ks = 0; ks < 8; ++ks) {
        const float* src = (ks < 4) ? (px + ks * 32) : (ps + (ks - 4) * 32);
        floatx4 f0 = *(const floatx4*)(src);
        floatx4 f1 = *(const floatx4*)(src + 4);
        if (ks >= 4) {
            f0 *= rcn;
            f1 *= rcn;
        }
        bf16x8 a;
#pragma unroll
        for (int j = 0; j < 4; ++j) {
            a[j] = (bf16_t)f0[j];
            a[j + 4] = (bf16_t)f1[j];
        }
        acc0 = MFMA(a, bf[0][ks], acc0);
        acc1 = MFMA(a, bf[1][ks], acc1);
    }
    __syncthreads();  // s == out in-place: all reads done before stores
#pragma unroll
    for (int r = 0; r < 4; ++r) {
        long ir = m0 + h * 4 + r;
        out[ir * GNN_H + n0 + li] = fmaxf(acc0[r] + bias0, 0.f);
        out[ir * GNN_H + n0 + 16 + li] = fmaxf(acc1[r] + bias1, 0.f);
    }
}

extern "C" void kernel_launch(void* const* d_in, const int* in_sizes, int n_in,
                              void* d_out, int out_size, void* d_ws, size_t ws_size,
                              hipStream_t stream) {
    const float* x = (const float*)d_in[0];
    const void* ei = d_in[1];
    const float* ea = (const float*)d_in[2];
    const float* W1 = (const float*)d_in[3];
    const float* b1 = (const float*)d_in[4];
    const float* W2 = (const float*)d_in[5];
    const float* b2 = (const float*)d_in[6];
    float* out = (float*)d_out;
    char* ws = (char*)d_ws;

    prep_kernel<<<32, 256, 0, stream>>>(W1, W2, (const int*)ei, ws);

    if (ws_size >= WS_V3) {
        int* cnt = (int*)(ws + OFF_CNT);
        int mode = (ws_size >= WS_V4) ? 1 : 0;
        hipMemsetAsync(cnt, 0, NN * 4, stream);
        hist_kernel<<<E_EDGES / 256, 256, 0, stream>>>(ei, ws, cnt);
        scan_kernel<<<1, 1024, 0, stream>>>(cnt, (int*)(ws + OFF_RP), (int*)(ws + OFF_WOFF));
        scatter_kernel<<<E_EDGES / 256, 256, 0, stream>>>(
            ei, ws, (int*)(ws + OFF_WOFF), (unsigned*)(ws + OFF_PERM),
            (unsigned long long*)(ws + OFF_PK64), mode);
        rc_kernel<<<NN / 16, 256, 0, stream>>>(x, ws);
        if (mode)
            fused_v4<<<NN / NB, 256, 0, stream>>>(x, ea, b1, b2, ws, out);
        else
            fused_v3<<<NN / NB, 256, 0, stream>>>(x, ei, ea, b1, b2, ws, out);
    } else {
        float* cntf = (float*)(ws + OFF_CNT);
        hipMemsetAsync(cntf, 0, NN * 4, stream);
        hipMemsetAsync(out, 0, (size_t)NN * GNN_H * 4, stream);
        count_kernel<<<E_EDGES / 256, 256, 0, stream>>>(ei, ws, cntf);
        edge_kernel<<<4096, 256, 0, stream>>>(x, ei, ea, b1, ws, out);
        node_kernel<<<NN / 16, 256, 0, stream>>>(x, b2, ws, cntf, out, out);
    }
}